// Round 9
// baseline (766.069 us; speedup 1.0000x reference)
//
#include <hip/hip_runtime.h>
#include <hip/hip_bf16.h>
#include <stdint.h>

#define NN 50000
#define NE 800000
#define NR 16
#define NP (NN * NR)                 // 800000 pair bins
#define NB1 ((NP + 255) / 256)       // 3125
#define NTILES ((NN + 127) / 128)    // 391

typedef unsigned short u16;
typedef unsigned int u32;

typedef __bf16 bf16x8 __attribute__((ext_vector_type(8)));
typedef __bf16 bf16x2 __attribute__((ext_vector_type(2)));
typedef float f32x4 __attribute__((ext_vector_type(4)));

__device__ __forceinline__ u16 f2bf(float f) {
  u32 u = __float_as_uint(f);
  u = u + 0x7FFFu + ((u >> 16) & 1u);
  return (u16)(u >> 16);
}

__device__ __forceinline__ u32 pk2bf(float x, float y) {
#if __has_builtin(__builtin_amdgcn_cvt_pk_bf16_f32)
  bf16x2 r = __builtin_amdgcn_cvt_pk_bf16_f32(x, y);
  union { bf16x2 v; u32 u; } c;
  c.v = r;
  return c.u;
#else
  return (u32)f2bf(x) | ((u32)f2bf(y) << 16);
#endif
}

__device__ __forceinline__ float bflo(u32 w) { return __uint_as_float(w << 16); }
__device__ __forceinline__ float bfhi(u32 w) { return __uint_as_float(w & 0xFFFF0000u); }

// ---------------- edge sort by (dst, rel) — counting sort over NP bins ----------------
__global__ void hist_kernel(const int* __restrict__ dst, const int* __restrict__ rel,
                            int* __restrict__ counts) {
  int e = blockIdx.x * 256 + threadIdx.x;
  if (e < NE) atomicAdd(&counts[dst[e] * NR + rel[e]], 1);
}

__global__ void scan_partial(const int* __restrict__ counts, int* __restrict__ bsum) {
  __shared__ int buf[256];
  int t = threadIdx.x;
  int i = blockIdx.x * 256 + t;
  int v = (i < NP) ? counts[i] : 0;
  buf[t] = v;
  __syncthreads();
  for (int off = 1; off < 256; off <<= 1) {
    int x = buf[t];
    int y = (t >= off) ? buf[t - off] : 0;
    __syncthreads();
    buf[t] = x + y;
    __syncthreads();
  }
  if (t == 255) bsum[blockIdx.x] = buf[255];
}

// single block, 1024 threads, 4-serial each: scans NB1 (<=4096) block sums
__global__ void scan_mid(const int* __restrict__ bsum, int* __restrict__ boff,
                         int* __restrict__ total_out) {
  __shared__ int buf[1024];
  int t = threadIdx.x;
  int v[4];
  int sum = 0;
#pragma unroll
  for (int i = 0; i < 4; ++i) {
    int idx = t * 4 + i;
    v[i] = (idx < NB1) ? bsum[idx] : 0;
    sum += v[i];
  }
  buf[t] = sum;
  __syncthreads();
  for (int off = 1; off < 1024; off <<= 1) {
    int x = buf[t];
    int y = (t >= off) ? buf[t - off] : 0;
    __syncthreads();
    buf[t] = x + y;
    __syncthreads();
  }
  int excl = buf[t] - sum;
#pragma unroll
  for (int i = 0; i < 4; ++i) {
    int idx = t * 4 + i;
    if (idx < NB1) { boff[idx] = excl; excl += v[i]; }
  }
  if (t == 1023) *total_out = buf[1023];
}

__global__ void scan_final(const int* __restrict__ counts, const int* __restrict__ boff,
                           int* __restrict__ starts, int* __restrict__ cursor) {
  __shared__ int buf[256];
  int t = threadIdx.x;
  int i = blockIdx.x * 256 + t;
  int v = (i < NP) ? counts[i] : 0;
  buf[t] = v;
  __syncthreads();
  for (int off = 1; off < 256; off <<= 1) {
    int x = buf[t];
    int y = (t >= off) ? buf[t - off] : 0;
    __syncthreads();
    buf[t] = x + y;
    __syncthreads();
  }
  int s = boff[blockIdx.x] + buf[t] - v;
  if (i < NP) {
    starts[i] = s;
    cursor[i] = s;
  }
}

// esd[pos] = { rel<<16 | src, norm_bits }
__global__ void scatter_kernel(const int* __restrict__ src, const int* __restrict__ dst,
                               const int* __restrict__ rel, const float* __restrict__ norm,
                               int* __restrict__ cursor, uint2* __restrict__ esd) {
  int e = blockIdx.x * 256 + threadIdx.x;
  if (e < NE) {
    int r = rel[e];
    int pos = atomicAdd(&cursor[dst[e] * NR + r], 1);
    esd[pos] = make_uint2(((u32)r << 16) | (u32)src[e], __float_as_uint(norm[e]));
  }
}

// ---------------- weight convert: Wt[mat][d][k] = bf16(W[mat][k][d]) ----------------
// mats 0..15 = w0 rels, 16 = lw0, 17..32 = w1 rels, 33 = lw1
__global__ void convert_wt(const float* __restrict__ w0, const float* __restrict__ lw0,
                           const float* __restrict__ w1, const float* __restrict__ lw1,
                           u16* __restrict__ Wt) {
  int m = blockIdx.y;
  int idx = blockIdx.x * 256 + threadIdx.x; // 0..16383
  int d = idx >> 7, k = idx & 127;
  const float* s;
  if (m < 16) s = w0 + (size_t)m * 16384;
  else if (m == 16) s = lw0;
  else if (m < 33) s = w1 + (size_t)(m - 17) * 16384;
  else s = lw1;
  Wt[(size_t)m * 16384 + idx] = f2bf(s[k * 128 + d]);
}

// ---------------- h f32 -> bf16 (layer 0 input only) ----------------
__global__ void hconv_kernel(const float* __restrict__ h, u16* __restrict__ hbf) {
  int i = blockIdx.x * 256 + threadIdx.x; // float4 index
  float4 v = ((const float4*)h)[i];
  ushort4 u;
  u.x = f2bf(v.x); u.y = f2bf(v.y); u.z = f2bf(v.z); u.w = f2bf(v.w);
  ((ushort4*)hbf)[i] = u;
}

// ---------------- gate table: gates[r][n] = sigmoid(hbf[n] . gw[r]) ----------------
__global__ void gates_kernel(const u16* __restrict__ hbf, const float* __restrict__ gw,
                             float* __restrict__ gates) {
  __shared__ float hs[16 * 132];
  __shared__ float gws[16 * 132];
  int t = threadIdx.x;
  int n0 = blockIdx.x * 16;
#pragma unroll
  for (int i = 0; i < 2; ++i) {
    int f = t + 256 * i;            // 0..511
    int row = f >> 5, c4 = (f & 31) * 4;
    ushort4 u = *(const ushort4*)&hbf[(size_t)(n0 + row) * 128 + c4];
    hs[row * 132 + c4 + 0] = __uint_as_float((u32)u.x << 16);
    hs[row * 132 + c4 + 1] = __uint_as_float((u32)u.y << 16);
    hs[row * 132 + c4 + 2] = __uint_as_float((u32)u.z << 16);
    hs[row * 132 + c4 + 3] = __uint_as_float((u32)u.w << 16);
    *(float4*)&gws[row * 132 + c4] = *(const float4*)&gw[row * 128 + c4];
  }
  __syncthreads();
  int nl = t >> 4, r = t & 15;
  float s = 0.f;
#pragma unroll 8
  for (int k = 0; k < 128; ++k) s += hs[nl * 132 + k] * gws[r * 132 + k];
  gates[r * NN + n0 + nl] = 1.f / (1.f + __expf(-s));
}

// ---------------- FUSED aggregate + GEMM ----------------
// out[v] = sum_{r=0..15} (sum_{e in bin(v,r)} gate·norm·hbf[src_e]) @ W_r
//          + hbf[v] @ loop_w + bias
// Per rel phase m: each wave builds its 32 rows of the 128x128 agg_m tile DIRECTLY
// IN LDS from the (dst,rel)-sorted edge array (bins avg 1 edge; batch 8 bins with
// first+second-edge prefetch, rare serial tail), then MFMA-accumulates into the
// persistent AGPR tile. Kills the 205 MB agg HBM round-trip (R8: agg write 200 MB
// + biggemm agg fetch 205 MB per layer = the 60%-of-peak BW wall).
// W pipeline = R8's spill-proofed named-register prefetch.

#define REP8(X) X(0) X(1) X(2) X(3) X(4) X(5) X(6) X(7)

#define W_ISSUE(i)                                                            \
  {                                                                           \
    int u8 = t + 256 * i;                                                     \
    int row = u8 >> 4, c8 = (u8 & 15) * 8;                                    \
    rw##i = *(const uint4*)&wbase[row * 128 + c8];                            \
  }

#define W_COMMIT(i)                                                           \
  {                                                                           \
    int u8 = t + 256 * i;                                                     \
    int row = u8 >> 4, c8 = (u8 & 15) * 8;                                    \
    *(uint4*)&Ws[row * 136 + c8] = rw##i;                                     \
  }

#define BG_MFMA                                                               \
  _Pragma("unroll")                                                           \
  for (int kk = 0; kk < 4; ++kk) {                                            \
    int k0 = kk * 32 + quad * 8;                                              \
    bf16x8 fa[4], fb[4];                                                      \
    _Pragma("unroll")                                                         \
    for (int i2 = 0; i2 < 4; ++i2)                                            \
      fa[i2] = *(const bf16x8*)&Ws[(wd + i2 * 16 + mrow) * 136 + k0];         \
    _Pragma("unroll")                                                         \
    for (int j2 = 0; j2 < 4; ++j2)                                            \
      fb[j2] = *(const bf16x8*)&As[(wn + j2 * 16 + mrow) * 136 + k0];         \
    _Pragma("unroll")                                                         \
    for (int i2 = 0; i2 < 4; ++i2)                                            \
      _Pragma("unroll")                                                       \
      for (int j2 = 0; j2 < 4; ++j2)                                          \
        acc[i2][j2] =                                                         \
            __builtin_amdgcn_mfma_f32_16x16x32_bf16(fa[i2], fb[j2],           \
                                                    acc[i2][j2], 0, 0, 0);    \
  }

template <int LAYER>
__global__ __launch_bounds__(256, 2)
void fused_kernel(const u16* __restrict__ hbf, const uint2* __restrict__ esd,
                  const float* __restrict__ gates, const int* __restrict__ starts,
                  const u16* __restrict__ Wt, const float* __restrict__ bias,
                  u16* __restrict__ hb_out, float* __restrict__ fout) {
  const u32* hbf32 = (const u32*)hbf;
  __shared__ u16 As[128 * 136]; // agg_m tile (node rows), pad +8
  __shared__ u16 Ws[128 * 136]; // W rows = d_out
  int t = threadIdx.x;
  int n0 = blockIdx.x * 128;
  int lane = t & 63;
  int wave = __builtin_amdgcn_readfirstlane(t >> 6); // force wave-uniform
  int wd = (wave & 1) * 64, wn = (wave >> 1) * 64;
  int mrow = lane & 15, quad = lane >> 4;
  int wrow0 = wave * 32;                 // this wave's As rows
  float4 bv[4];
#pragma unroll
  for (int i = 0; i < 4; ++i) bv[i] = *(const float4*)&bias[wd + i * 16 + quad * 4];
  f32x4 acc[4][4];
#pragma unroll
  for (int i = 0; i < 4; ++i)
#pragma unroll
    for (int j = 0; j < 4; ++j) acc[i][j] = (f32x4){0.f, 0.f, 0.f, 0.f};

  uint4 rw0, rw1, rw2, rw3, rw4, rw5, rw6, rw7;
  const u16* wbase = Wt;
  REP8(W_ISSUE)                          // prefetch W for m=0
  for (int m = 0; m < 16; ++m) {
    // ---- build As rows for rel m (one group of 8 bins in flight; groups rolled
    //      to bound register pressure — R7 lesson) ----
#pragma unroll 1
    for (int g = 0; g < 4; ++g) {
      int vb = n0 + wrow0 + g * 8;
      int s_[8], c_[8];
#pragma unroll
      for (int i = 0; i < 8; ++i) {
        int v = vb + i;
        int vc = v < NN ? v : NN - 1;
        int bin = vc * 16 + m;           // wave-uniform -> s_load
        int s0 = starts[bin];
        int e0 = starts[bin + 1];
        s_[i] = s0;
        c_[i] = v < NN ? e0 - s0 : 0;
      }
      uint2 p1[8], p2[8];
      u32 h1[8], h2[8];
      float g1[8], g2[8];
#pragma unroll
      for (int i = 0; i < 8; ++i) {
        int e1 = s_[i] < NE ? s_[i] : NE - 1;       // clamp (empty bins read junk,
        int e2 = s_[i] + 1 < NE ? s_[i] + 1 : NE - 1; // masked by c_ below)
        p1[i] = esd[e1];
        p2[i] = esd[e2];
      }
#pragma unroll
      for (int i = 0; i < 8; ++i) {
        u32 sn1 = p1[i].x & 0xFFFFu;
        u32 sn2 = p2[i].x & 0xFFFFu;
        h1[i] = hbf32[sn1 * 64u + (u32)lane];       // L3-resident gather
        h2[i] = hbf32[sn2 * 64u + (u32)lane];
        g1[i] = gates[(p1[i].x >> 16) * (u32)NN + sn1];
        g2[i] = gates[(p2[i].x >> 16) * (u32)NN + sn2];
      }
#pragma unroll
      for (int i = 0; i < 8; ++i) {
        float a0 = 0.f, a1 = 0.f;
        if (c_[i] >= 1) {                           // wave-uniform branches
          float coef = g1[i] * __uint_as_float(p1[i].y);
          a0 = coef * bflo(h1[i]);
          a1 = coef * bfhi(h1[i]);
        }
        if (c_[i] >= 2) {
          float coef = g2[i] * __uint_as_float(p2[i].y);
          a0 = fmaf(coef, bflo(h2[i]), a0);
          a1 = fmaf(coef, bfhi(h2[i]), a1);
        }
        int jend = s_[i] + c_[i];
        for (int j = s_[i] + 2; j < jend; ++j) {    // rare (P~8%) serial tail
          uint2 p = esd[j];
          u32 sn = p.x & 0xFFFFu;
          float coef = gates[(p.x >> 16) * (u32)NN + sn] * __uint_as_float(p.y);
          u32 hv = hbf32[sn * 64u + (u32)lane];
          a0 = fmaf(coef, bflo(hv), a0);
          a1 = fmaf(coef, bfhi(hv), a1);
        }
        *(u32*)&As[(wrow0 + g * 8 + i) * 136 + lane * 2] = pk2bf(a0, a1);
      }
    }
    REP8(W_COMMIT)                       // rw prefetched a full phase ago
    __syncthreads();
    wbase = Wt + (size_t)(m + 1) * 16384;
    REP8(W_ISSUE)                        // fire next mat's W; no wait until commit
    BG_MFMA
    __syncthreads();                     // all waves done reading LDS
  }
  // ---- peeled m=16: self-loop, As rows = hbf rows (cooperative staging) ----
#pragma unroll
  for (int i = 0; i < 8; ++i) {
    int u8 = t + 256 * i;
    int row = u8 >> 4, c8 = (u8 & 15) * 8;
    int n = n0 + row;
    int nc = n < NN ? n : NN - 1;        // clamp: garbage rows never stored
    *(uint4*)&As[row * 136 + c8] = *(const uint4*)&hbf[(size_t)nc * 128 + c8];
  }
  REP8(W_COMMIT)
  __syncthreads();
  BG_MFMA

  // epilogue: lane owns node = n0+wn+j*16+mrow, d = wd+i*16+quad*4 .. +3 (contiguous)
#pragma unroll
  for (int j = 0; j < 4; ++j) {
    int n = n0 + wn + j * 16 + mrow;
    if (n < NN) {
#pragma unroll
      for (int i = 0; i < 4; ++i) {
        int d0 = wd + i * 16 + quad * 4;
        float v0 = acc[i][j][0] + bv[i].x;
        float v1 = acc[i][j][1] + bv[i].y;
        float v2 = acc[i][j][2] + bv[i].z;
        float v3 = acc[i][j][3] + bv[i].w;
        if (LAYER == 0) {
          v0 = fmaxf(v0, 0.f); v1 = fmaxf(v1, 0.f);
          v2 = fmaxf(v2, 0.f); v3 = fmaxf(v3, 0.f);
          uint2 st;
          st.x = pk2bf(v0, v1);
          st.y = pk2bf(v2, v3);
          *(uint2*)&hb_out[(size_t)n * 128 + d0] = st;
        } else {
          float4 st = make_float4(v0, v1, v2, v3);
          *(float4*)&fout[(size_t)n * 128 + d0] = st;
        }
      }
    }
  }
}

// ---------------- host ----------------
extern "C" void kernel_launch(void* const* d_in, const int* in_sizes, int n_in,
                              void* d_out, int out_size, void* d_ws, size_t ws_size,
                              hipStream_t stream) {
  const float* h0   = (const float*)d_in[0];
  const float* norm = (const float*)d_in[1];
  const float* w0   = (const float*)d_in[2];
  const float* b0   = (const float*)d_in[3];
  const float* lw0  = (const float*)d_in[4];
  const float* gw0  = (const float*)d_in[5];
  const float* w1   = (const float*)d_in[6];
  const float* b1   = (const float*)d_in[7];
  const float* lw1  = (const float*)d_in[8];
  const float* gw1  = (const float*)d_in[9];
  const int*   src  = (const int*)d_in[10];
  const int*   dst  = (const int*)d_in[11];
  const int*   rel  = (const int*)d_in[12];
  float* out = (float*)d_out;

  char* p = (char*)d_ws;
  auto alloc = [&](size_t bytes) -> void* {
    void* q = (void*)p;
    p += (bytes + 255) & ~(size_t)255;
    return q;
  };
  u16*   Wt     = (u16*)alloc((size_t)34 * 16384 * 2);
  float* gates  = (float*)alloc((size_t)NR * NN * 4);
  u16*   hbf0   = (u16*)alloc((size_t)NN * 128 * 2);
  u16*   hbf1   = (u16*)alloc((size_t)NN * 128 * 2);
  int*   counts = (int*)alloc((size_t)NP * 4);
  int*   cursor = (int*)alloc((size_t)NP * 4);
  int*   starts = (int*)alloc((size_t)(NP + 1) * 4);
  int*   bsum   = (int*)alloc((size_t)NB1 * 4);
  int*   boff   = (int*)alloc((size_t)NB1 * 4);
  uint2* esd    = (uint2*)alloc((size_t)NE * 8);

  // ---- sort edges by (dst, rel) — shared by both layers ----
  hipMemsetAsync(counts, 0, (size_t)NP * 4, stream);
  hist_kernel<<<NE / 256, 256, 0, stream>>>(dst, rel, counts);
  scan_partial<<<NB1, 256, 0, stream>>>(counts, bsum);
  scan_mid<<<1, 1024, 0, stream>>>(bsum, boff, starts + NP);
  scan_final<<<NB1, 256, 0, stream>>>(counts, boff, starts, cursor);
  scatter_kernel<<<NE / 256, 256, 0, stream>>>(src, dst, rel, norm, cursor, esd);
  convert_wt<<<dim3(64, 34), 256, 0, stream>>>(w0, lw0, w1, lw1, Wt);
  hconv_kernel<<<NN * 32 / 256, 256, 0, stream>>>(h0, hbf0);

  // ---- layer 0 (relu, bf16 output) ----
  gates_kernel<<<NN / 16, 256, 0, stream>>>(hbf0, gw0, gates);
  fused_kernel<0><<<NTILES, 256, 0, stream>>>(
      hbf0, esd, gates, starts, Wt, b0, hbf1, nullptr);

  // ---- layer 1 (no relu, f32 output) ----
  gates_kernel<<<NN / 16, 256, 0, stream>>>(hbf1, gw1, gates);
  fused_kernel<1><<<NTILES, 256, 0, stream>>>(
      hbf1, esd, gates, starts, Wt + (size_t)17 * 16384, b1, nullptr, out);
}